// Round 3
// baseline (453.650 us; speedup 1.0000x reference)
//
#include <hip/hip_runtime.h>

typedef __attribute__((ext_vector_type(8))) short bf16x8;
typedef __attribute__((ext_vector_type(4))) float f32x4;

// pack two fp32 -> two bf16 (round-half-up) in one v_perm_b32
__device__ __forceinline__ unsigned pk2(float f0, float f1) {
  return __builtin_amdgcn_perm(__float_as_uint(f1) + 0x8000u,
                               __float_as_uint(f0) + 0x8000u, 0x07060302u);
}
__device__ __forceinline__ short f2bf_s(float f) {
  return (short)((__float_as_uint(f) + 0x8000u) >> 16);
}
__device__ __forceinline__ float bf2f(short s) {
  return __uint_as_float(((unsigned)(unsigned short)s) << 16);
}

// ---------------------------------------------------------------------------
// K1: full-res conv 192->64 + bias + relu; also emits compact down4 copy.
// v4: M-split for concurrency. Each wave computes 32 output channels x 64 px
// (acc = 32 VGPR); two waves share a pixel group (duplicate activation reads
// are L1/L2 hits). Grid 2048 blocks = 8192 waves = 32 waves/CU offered vs
// 4096 waves before -- the wave count, not per-wave scheduling, was the BW
// limiter (R0/R1/R2 all ~1.6 TB/s at 6-11 waves/CU).
// block: wv>>1 = pixel group (2 x 64 px), wv&1 = channel half (2 x 32 ch).
// ---------------------------------------------------------------------------
__global__ __launch_bounds__(256, 6) void k1_conv192(
    const float* __restrict__ x1, const float* __restrict__ x2,
    const float* __restrict__ w0, const float* __restrict__ b0,
    float* __restrict__ xout, short* __restrict__ xds)
{
  const int b    = blockIdx.y;
  const int wv   = threadIdx.x >> 6;
  const int lane = threadIdx.x & 63;
  const int quad = lane >> 4;
  const int l16  = lane & 15;
  const int pxg  = wv >> 1;                    // 0..1
  const int mh   = wv & 1;                     // 0..1
  const int n0   = blockIdx.x * 128 + pxg * 64;
  const int mb   = mh * 32;

  f32x4 acc[2][4];
  #pragma unroll
  for (int mt = 0; mt < 2; ++mt)
    #pragma unroll
    for (int nt = 0; nt < 4; ++nt)
      acc[mt][nt] = (f32x4){0.f, 0.f, 0.f, 0.f};

  #pragma unroll
  for (int kc = 0; kc < 6; ++kc) {
    const float* src = (kc < 4)
        ? (x1 + ((long)b * 128 + kc * 32) * 65536)
        : (x2 + ((long)b * 64 + (kc - 4) * 32) * 65536);
    const float* s8 = src + (long)(quad * 8) * 65536;

    // activation k-tile: 32 dwords/lane, independent -> deep VMEM queue
    float e[4][8];
    #pragma unroll
    for (int nt = 0; nt < 4; ++nt) {
      const int p = n0 + nt * 16 + l16;
      #pragma unroll
      for (int j = 0; j < 8; ++j) e[nt][j] = s8[(long)j * 65536 + p];
    }

    // weight fragments for this wave's 32 output channels (L2-hot)
    bf16x8 af[2];
    #pragma unroll
    for (int mt = 0; mt < 2; ++mt) {
      const float* wrow = w0 + (mb + mt * 16 + l16) * 192 + kc * 32 + quad * 8;
      float4 wa = *(const float4*)wrow;
      float4 wb = *(const float4*)(wrow + 4);
      union { unsigned i[4]; bf16x8 v; } u;
      u.i[0] = pk2(wa.x, wa.y); u.i[1] = pk2(wa.z, wa.w);
      u.i[2] = pk2(wb.x, wb.y); u.i[3] = pk2(wb.z, wb.w);
      af[mt] = u.v;
    }

    bf16x8 bfv[4];
    #pragma unroll
    for (int nt = 0; nt < 4; ++nt) {
      union { unsigned i[4]; bf16x8 v; } u;
      #pragma unroll
      for (int j = 0; j < 4; ++j) u.i[j] = pk2(e[nt][2 * j], e[nt][2 * j + 1]);
      bfv[nt] = u.v;
    }
    #pragma unroll
    for (int mt = 0; mt < 2; ++mt)
      #pragma unroll
      for (int nt = 0; nt < 4; ++nt)
        acc[mt][nt] = __builtin_amdgcn_mfma_f32_16x16x32_bf16(
            af[mt], bfv[nt], acc[mt][nt], 0, 0, 0);
  }

  #pragma unroll
  for (int mt = 0; mt < 2; ++mt) {
    const float4 bb = *(const float4*)(b0 + mb + mt * 16 + quad * 4);
    #pragma unroll
    for (int r = 0; r < 4; ++r) {
      const int o = mb + mt * 16 + quad * 4 + r;
      const float bias = (r == 0) ? bb.x : (r == 1) ? bb.y : (r == 2) ? bb.z : bb.w;
      float* orow = xout + ((long)b * 64 + o) * 65536;
      #pragma unroll
      for (int nt = 0; nt < 4; ++nt)
        orow[n0 + nt * 16 + l16] = fmaxf(acc[mt][nt][r] + bias, 0.f);
    }
  }

  // compact down4 copy: rows h%4==0 -> blocks with (bx>>1)%4==0, cols w%4==0
  if (((blockIdx.x & 6) == 0) && ((l16 & 3) == 0)) {
    const int nbase = (blockIdx.x >> 3) * 64 + (blockIdx.x & 1) * 32 +
                      pxg * 16 + (l16 >> 2);
    #pragma unroll
    for (int mt = 0; mt < 2; ++mt) {
      const float4 bb = *(const float4*)(b0 + mb + mt * 16 + quad * 4);
      #pragma unroll
      for (int nt = 0; nt < 4; ++nt) {
        const float v0 = fmaxf(acc[mt][nt][0] + bb.x, 0.f);
        const float v1 = fmaxf(acc[mt][nt][1] + bb.y, 0.f);
        const float v2 = fmaxf(acc[mt][nt][2] + bb.z, 0.f);
        const float v3 = fmaxf(acc[mt][nt][3] + bb.w, 0.f);
        union { unsigned i[2]; unsigned long long q; } u;
        u.i[0] = pk2(v0, v1); u.i[1] = pk2(v2, v3);
        const int n = nbase + nt * 4;
        *(unsigned long long*)(xds + ((long)b * 4096 + n) * 64 +
                               mb + mt * 16 + quad * 4) = u.q;
      }
    }
  }
}

// ---------------------------------------------------------------------------
// K2: down4-res convs as chained 64x64x64 MFMA GEMMs through LDS (unchanged)
// ---------------------------------------------------------------------------
__device__ __forceinline__ void loadw_frag(const float* __restrict__ w,
                                           int row, int quad, bf16x8 wf[2]) {
  #pragma unroll
  for (int kc = 0; kc < 2; ++kc) {
    const float* p = w + row * 64 + kc * 32 + quad * 8;
    float4 a = *(const float4*)p;
    float4 c = *(const float4*)(p + 4);
    union { unsigned i[4]; bf16x8 v; } u;
    u.i[0] = pk2(a.x, a.y); u.i[1] = pk2(a.z, a.w);
    u.i[2] = pk2(c.x, c.y); u.i[3] = pk2(c.z, c.w);
    wf[kc] = u.v;
  }
}

__device__ __forceinline__ void conv_mfma(const short (*src)[72], short (*dst)[72],
                                          const bf16x8* wf,
                                          const float* __restrict__ bias,
                                          int ch0, int l16, int quad) {
  const float4 bv4 = *(const float4*)(bias + ch0);
  #pragma unroll
  for (int nt = 0; nt < 4; ++nt) {
    f32x4 acc = (f32x4){0.f, 0.f, 0.f, 0.f};
    #pragma unroll
    for (int kc = 0; kc < 2; ++kc) {
      bf16x8 bv = *(const bf16x8*)&src[nt * 16 + l16][kc * 32 + quad * 8];
      acc = __builtin_amdgcn_mfma_f32_16x16x32_bf16(wf[kc], bv, acc, 0, 0, 0);
    }
    const float v0 = fmaxf(acc[0] + bv4.x, 0.f);
    const float v1 = fmaxf(acc[1] + bv4.y, 0.f);
    const float v2 = fmaxf(acc[2] + bv4.z, 0.f);
    const float v3 = fmaxf(acc[3] + bv4.w, 0.f);
    union { unsigned i[2]; unsigned long long q; } u;
    u.i[0] = pk2(v0, v1); u.i[1] = pk2(v2, v3);
    *(unsigned long long*)&dst[nt * 16 + l16][ch0] = u.q;
  }
}

__global__ __launch_bounds__(256) void k2_small(
    const short* __restrict__ xds, const float* __restrict__ event,
    const float* __restrict__ xw1, const float* __restrict__ xb1,
    const float* __restrict__ ew0, const float* __restrict__ eb0,
    const float* __restrict__ ew1, const float* __restrict__ eb1,
    const float* __restrict__ qw, const float* __restrict__ qb,
    const float* __restrict__ kw, const float* __restrict__ kb,
    const float* __restrict__ vw, const float* __restrict__ vb,
    short* __restrict__ q_pm, short* __restrict__ k_pm,
    short* __restrict__ v_cm, short* __restrict__ ef_cm)
{
  __shared__ short A[64][72], Bb[64][72], Cb[64][72];
  const int b    = blockIdx.y;
  const int h4   = blockIdx.x;
  const int t    = threadIdx.x;
  const int lane = t & 63;
  const int g    = t >> 6;
  const int quad = lane >> 4;
  const int l16  = lane & 15;
  const int row  = g * 16 + l16;
  const int ch0  = g * 16 + quad * 4;

  bf16x8 wfx1[2], wfq[2], wfv[2], wfe0[2], wfe1[2], wfk[2];
  loadw_frag(xw1, row, quad, wfx1);
  loadw_frag(qw,  row, quad, wfq);
  loadw_frag(vw,  row, quad, wfv);
  loadw_frag(ew0, row, quad, wfe0);
  loadw_frag(ew1, row, quad, wfe1);
  loadw_frag(kw,  row, quad, wfk);

  const int px  = t >> 2;
  const int seg = t & 3;
  {
    const short* s = xds + ((long)b * 4096 + h4 * 64 + px) * 64 + seg * 16;
    *(bf16x8*)&A[px][seg * 16]     = *(const bf16x8*)s;
    *(bf16x8*)&A[px][seg * 16 + 8] = *(const bf16x8*)(s + 8);
  }
  __syncthreads();
  conv_mfma(A, Bb, wfx1, xb1, ch0, l16, quad);
  __syncthreads();
  conv_mfma(Bb, A,  wfq, qb, ch0, l16, quad);
  conv_mfma(Bb, Cb, wfv, vb, ch0, l16, quad);
  __syncthreads();
  {
    short* qdst = q_pm + ((long)b * 4096 + h4 * 64 + px) * 64 + seg * 16;
    *(bf16x8*)qdst       = *(const bf16x8*)&A[px][seg * 16];
    *(bf16x8*)(qdst + 8) = *(const bf16x8*)&A[px][seg * 16 + 8];
    union { short s[16]; int4 q2[2]; } vv;
    #pragma unroll
    for (int i = 0; i < 16; ++i) vv.s[i] = Cb[seg * 16 + i][px];
    int4* vdst = (int4*)(v_cm + ((long)b * 64 + px) * 4096 + h4 * 64 + seg * 16);
    vdst[0] = vv.q2[0]; vdst[1] = vv.q2[1];
    const int px2 = t & 63, cg = t >> 6;
    const float* ev = event + (long)b * 64 * 65536 + (long)h4 * 1024 + px2 * 4;
    #pragma unroll
    for (int r = 0; r < 16; r += 2) {
      const float e0v = ev[(long)(cg * 16 + r) * 65536];
      const float e1v = ev[(long)(cg * 16 + r + 1) * 65536];
      *(unsigned*)&Bb[px2][cg * 16 + r] = pk2(e0v, e1v);
    }
  }
  __syncthreads();
  conv_mfma(Bb, A,  wfe0, eb0, ch0, l16, quad);
  __syncthreads();
  conv_mfma(A,  Cb, wfe1, eb1, ch0, l16, quad);
  __syncthreads();
  conv_mfma(Cb, Bb, wfk, kb, ch0, l16, quad);
  {
    union { short s[16]; int4 q2[2]; } vv;
    #pragma unroll
    for (int i = 0; i < 16; ++i) vv.s[i] = Cb[seg * 16 + i][px];
    int4* edst = (int4*)(ef_cm + ((long)b * 64 + px) * 4096 + h4 * 64 + seg * 16);
    edst[0] = vv.q2[0]; edst[1] = vv.q2[1];
  }
  __syncthreads();
  {
    short* kdst = k_pm + ((long)b * 4096 + h4 * 64 + px) * 64 + seg * 16;
    *(bf16x8*)kdst       = *(const bf16x8*)&Bb[px][seg * 16];
    *(bf16x8*)(kdst + 8) = *(const bf16x8*)&Bb[px][seg * 16 + 8];
  }
}

// ---------------------------------------------------------------------------
// K3: flash attention, transposed orientation, split-K by 4. (unchanged)
// ---------------------------------------------------------------------------
__global__ __launch_bounds__(256, 4) void k3_attn(
    const short* __restrict__ q_pm, const short* __restrict__ k_pm,
    const short* __restrict__ v_cm, short* __restrict__ Opart,
    float* __restrict__ ml)
{
  __shared__ short Kf[2][4096];
  __shared__ short Vf[2][4096];
  __shared__ short Pf[4][2][512];
  const int b    = blockIdx.y;
  const int ks   = blockIdx.z;
  const int q0   = blockIdx.x * 64;
  const int t    = threadIdx.x;
  const int wv   = __builtin_amdgcn_readfirstlane(t >> 6);
  const int lane = t & 63;
  const int quad = lane >> 4;
  const int l16  = lane & 15;

  bf16x8 qf[2];
  {
    const short* qp = q_pm + ((long)b * 4096 + q0 + wv * 16 + l16) * 64 + quad * 8;
    qf[0] = *(const bf16x8*)qp;
    qf[1] = *(const bf16x8*)(qp + 32);
  }

  const int srow  = t >> 2;
  const int seg   = t & 3;
  const int doff0 = (((seg >> 1) * 4 + (srow >> 4)) * 64 +
                     ((seg & 1) * 2) * 16 + (srow & 15)) * 8;
  const short* kbase = k_pm + (long)b * 4096 * 64;
  const short* vbase = v_cm + (long)b * 64 * 4096;
  const int kt0 = ks * 16;

  bf16x8 krg[2], vrg[2];
  {
    const short* s = kbase + (long)(kt0 * 64 + srow) * 64 + seg * 16;
    krg[0] = *(const bf16x8*)s; krg[1] = *(const bf16x8*)(s + 8);
    const short* v = vbase + (long)srow * 4096 + kt0 * 64 + seg * 16;
    vrg[0] = *(const bf16x8*)v; vrg[1] = *(const bf16x8*)(v + 8);
  }
  *(bf16x8*)&Kf[0][doff0]       = krg[0];
  *(bf16x8*)&Kf[0][doff0 + 128] = krg[1];
  *(bf16x8*)&Vf[0][doff0]       = vrg[0];
  *(bf16x8*)&Vf[0][doff0 + 128] = vrg[1];
  __syncthreads();

  f32x4 oacc[4];
  #pragma unroll
  for (int f = 0; f < 4; ++f) oacc[f] = (f32x4){0, 0, 0, 0};
  float run_m = -1e30f, run_l = 0.f;

  for (int kt = 0; kt < 16; ++kt) {
    if (kt < 15) {
      const int k0 = (kt0 + kt + 1) * 64;
      const short* s = kbase + (long)(k0 + srow) * 64 + seg * 16;
      krg[0] = *(const bf16x8*)s; krg[1] = *(const bf16x8*)(s + 8);
      const short* v = vbase + (long)srow * 4096 + k0 + seg * 16;
      vrg[0] = *(const bf16x8*)v; vrg[1] = *(const bf16x8*)(v + 8);
    }
    const int buf = kt & 1;

    f32x4 st[4];
    #pragma unroll
    for (int f = 0; f < 4; ++f) st[f] = (f32x4){0, 0, 0, 0};
    #pragma unroll
    for (int kc = 0; kc < 2; ++kc)
      #pragma unroll
      for (int f = 0; f < 4; ++f) {
        bf16x8 ka = *(const bf16x8*)&Kf[buf][((kc * 4 + f) * 64 + lane) * 8];
        st[f] = __builtin_amdgcn_mfma_f32_16x16x32_bf16(ka, qf[kc], st[f], 0, 0, 0);
      }

    float tm = st[0][0];
    #pragma unroll
    for (int f = 0; f < 4; ++f)
      #pragma unroll
      for (int r = 0; r < 4; ++r) tm = fmaxf(tm, st[f][r]);
    tm = fmaxf(tm, __shfl_xor(tm, 16));
    tm = fmaxf(tm, __shfl_xor(tm, 32));
    const float nm = fmaxf(run_m, tm);
    const float al = __expf(run_m - nm);
    run_m = nm;
    float pf[4][4], ts = 0.f;
    #pragma unroll
    for (int f = 0; f < 4; ++f)
      #pragma unroll
      for (int r = 0; r < 4; ++r) {
        pf[f][r] = __expf(st[f][r] - nm);
        ts += pf[f][r];
      }
    ts += __shfl_xor(ts, 16);
    ts += __shfl_xor(ts, 32);
    run_l = run_l * al + ts;
    #pragma unroll
    for (int f = 0; f < 4; ++f)
      #pragma unroll
      for (int r = 0; r < 4; ++r) oacc[f][r] *= al;

    #pragma unroll
    for (int f = 0; f < 4; ++f) {
      union { unsigned i[2]; unsigned long long q; } u;
      u.i[0] = pk2(pf[f][0], pf[f][1]);
      u.i[1] = pk2(pf[f][2], pf[f][3]);
      const int qd = (f & 1) * 2 + (quad >> 1);
      *(unsigned long long*)&Pf[wv][f >> 1][(qd * 16 + l16) * 8 + (quad & 1) * 4] = u.q;
    }
    #pragma unroll
    for (int kc = 0; kc < 2; ++kc) {
      bf16x8 pb = *(const bf16x8*)&Pf[wv][kc][lane * 8];
      #pragma unroll
      for (int f = 0; f < 4; ++f) {
        bf16x8 va = *(const bf16x8*)&Vf[buf][((kc * 4 + f) * 64 + lane) * 8];
        oacc[f] = __builtin_amdgcn_mfma_f32_16x16x32_bf16(va, pb, oacc[f], 0, 0, 0);
      }
    }

    if (kt < 15) {
      const int nb = buf ^ 1;
      *(bf16x8*)&Kf[nb][doff0]       = krg[0];
      *(bf16x8*)&Kf[nb][doff0 + 128] = krg[1];
      *(bf16x8*)&Vf[nb][doff0]       = vrg[0];
      *(bf16x8*)&Vf[nb][doff0 + 128] = vrg[1];
      __syncthreads();
    }
  }

  const int q = q0 + wv * 16 + l16;
  #pragma unroll
  for (int f = 0; f < 4; ++f)
    #pragma unroll
    for (int r = 0; r < 4; ++r) {
      const int ch = f * 16 + quad * 4 + r;
      Opart[((long)(ks * 4 + b) * 64 + ch) * 4096 + q] = f2bf_s(oacc[f][r]);
    }
  if (quad == 0) {
    float2 v = make_float2(run_m, run_l);
    *(float2*)&ml[((long)(ks * 4 + b) * 4096 + q) * 2] = v;
  }
}

// ---------------------------------------------------------------------------
// K3W: combine weights per (b,q) (unchanged)
// ---------------------------------------------------------------------------
__global__ __launch_bounds__(256) void k3w(const float* __restrict__ ml,
                                           float* __restrict__ wc)
{
  const int idx = blockIdx.x * 256 + threadIdx.x;
  const float2* m2 = (const float2*)ml;
  float2 s0 = m2[0 * 16384 + idx];
  float2 s1 = m2[1 * 16384 + idx];
  float2 s2 = m2[2 * 16384 + idx];
  float2 s3 = m2[3 * 16384 + idx];
  const float M = fmaxf(fmaxf(s0.x, s1.x), fmaxf(s2.x, s3.x));
  const float e0 = __expf(s0.x - M), e1 = __expf(s1.x - M);
  const float e2 = __expf(s2.x - M), e3 = __expf(s3.x - M);
  const float inv = 1.f / (e0 * s0.y + e1 * s1.y + e2 * s2.y + e3 * s3.y);
  *(float4*)&wc[idx * 4] = make_float4(e0 * inv, e1 * inv, e2 * inv, e3 * inv);
}

// ---------------------------------------------------------------------------
// K4: out = x + THITA*gamma*up4(combine(Opart));  ef_up = up4(ef). (unchanged)
// ---------------------------------------------------------------------------
__global__ __launch_bounds__(256) void k4_final(
    const short* __restrict__ Opart, const float* __restrict__ wc,
    const short* __restrict__ ef_cm, const float* __restrict__ gamma,
    float* __restrict__ dout)
{
  const long idx = (long)blockIdx.x * 256 + threadIdx.x;
  const long e4 = idx * 4;
  const int hw = (int)(e4 & 65535);
  const int bc = (int)(e4 >> 16);
  const int h = hw >> 8, w0 = hw & 255;
  const int n = (h >> 2) * 64 + (w0 >> 2);
  const int b = bc >> 6, c = bc & 63;
  const float s = 1e-4f * gamma[0];
  const float4 w4 = *(const float4*)&wc[((long)b * 4096 + n) * 4];
  const long obase = ((long)b * 64 + c) * 4096 + n;
  float ov = w4.x * bf2f(Opart[obase]) +
             w4.y * bf2f(Opart[obase + (long)1 * 4 * 64 * 4096]) +
             w4.z * bf2f(Opart[obase + (long)2 * 4 * 64 * 4096]) +
             w4.w * bf2f(Opart[obase + (long)3 * 4 * 64 * 4096]);
  ov *= s;
  float4 xv = *(float4*)(dout + e4);
  xv.x += ov; xv.y += ov; xv.z += ov; xv.w += ov;
  *(float4*)(dout + e4) = xv;
  const float ef = bf2f(ef_cm[(long)bc * 4096 + n]);
  *(float4*)(dout + 16777216 + e4) = make_float4(ef, ef, ef, ef);
}

extern "C" void kernel_launch(void* const* d_in, const int* in_sizes, int n_in,
                              void* d_out, int out_size, void* d_ws, size_t ws_size,
                              hipStream_t stream)
{
  const float* x1    = (const float*)d_in[0];
  const float* x2    = (const float*)d_in[1];
  const float* event = (const float*)d_in[2];
  const float* xw0   = (const float*)d_in[3];
  const float* xb0   = (const float*)d_in[4];
  const float* xw1   = (const float*)d_in[5];
  const float* xb1   = (const float*)d_in[6];
  const float* ew0   = (const float*)d_in[7];
  const float* eb0   = (const float*)d_in[8];
  const float* ew1   = (const float*)d_in[9];
  const float* eb1   = (const float*)d_in[10];
  const float* qw    = (const float*)d_in[11];
  const float* qb    = (const float*)d_in[12];
  const float* kw    = (const float*)d_in[13];
  const float* kb    = (const float*)d_in[14];
  const float* vw    = (const float*)d_in[15];
  const float* vb    = (const float*)d_in[16];
  const float* gamma = (const float*)d_in[17];
  float* dout = (float*)d_out;

  char* ws = (char*)d_ws;
  short* q_pm  = (short*)(ws);
  short* k_pm  = (short*)(ws + (2u << 20));
  short* v_cm  = (short*)(ws + (4u << 20));
  short* ef_cm = (short*)(ws + (6u << 20));
  short* xds   = (short*)(ws + (8u << 20));
  short* Opart = (short*)(ws + (10u << 20));
  float* ml    = (float*)(ws + (18u << 20));
  float* wc    = (float*)(ws + (18u << 20) + (512u << 10));

  k1_conv192<<<dim3(512, 4), 256, 0, stream>>>(x1, x2, xw0, xb0, dout, xds);
  k2_small<<<dim3(64, 4), 256, 0, stream>>>(xds, event, xw1, xb1, ew0, eb0,
                                            ew1, eb1, qw, qb, kw, kb, vw, vb,
                                            q_pm, k_pm, v_cm, ef_cm);
  k3_attn<<<dim3(64, 4, 4), 256, 0, stream>>>(q_pm, k_pm, v_cm, Opart, ml);
  k3w<<<64, 256, 0, stream>>>(ml, wc);
  k4_final<<<16384, 256, 0, stream>>>(Opart, wc, ef_cm, gamma, dout);
}

// Round 4
// 419.019 us; speedup vs baseline: 1.0826x; 1.0826x over previous
//
#include <hip/hip_runtime.h>

typedef __attribute__((ext_vector_type(8))) short bf16x8;
typedef __attribute__((ext_vector_type(4))) float f32x4;

// pack two fp32 -> two bf16 (round-half-up) in one v_perm_b32
__device__ __forceinline__ unsigned pk2(float f0, float f1) {
  return __builtin_amdgcn_perm(__float_as_uint(f1) + 0x8000u,
                               __float_as_uint(f0) + 0x8000u, 0x07060302u);
}
__device__ __forceinline__ short f2bf_s(float f) {
  return (short)((__float_as_uint(f) + 0x8000u) >> 16);
}
__device__ __forceinline__ float bf2f(short s) {
  return __uint_as_float(((unsigned)(unsigned short)s) << 16);
}

// ---------------------------------------------------------------------------
// K1: full-res conv 192->64 + bias + relu; also emits compact down4 copy.
// v5: R0 structure, but float4 (16B/lane) loads AND stores. Column mapping
// re-permuted so the float4 components feed the 4 nt-tiles directly:
// MFMA column l16 of tile nt <-> pixel n0 + 4*l16 + nt. No shuffles needed;
// loads drop 32->8 instrs/ktile, stores 64->16. Tests whether the ~1.7 TB/s
// wall (constant across R0-R3 schedules/occupancies) is request-width-bound.
// ---------------------------------------------------------------------------
__global__ __launch_bounds__(256, 2) void k1_conv192(
    const float* __restrict__ x1, const float* __restrict__ x2,
    const float* __restrict__ w0, const float* __restrict__ b0,
    float* __restrict__ xout, short* __restrict__ xds)
{
  const int b    = blockIdx.y;
  const int wv   = threadIdx.x >> 6;
  const int lane = threadIdx.x & 63;
  const int quad = lane >> 4;
  const int l16  = lane & 15;
  const int n0   = blockIdx.x * 256 + wv * 64;
  const int pxl  = n0 + 4 * l16;            // this lane's first pixel

  f32x4 acc[4][4];
  #pragma unroll
  for (int mt = 0; mt < 4; ++mt)
    #pragma unroll
    for (int nt = 0; nt < 4; ++nt)
      acc[mt][nt] = (f32x4){0.f, 0.f, 0.f, 0.f};

  #pragma unroll
  for (int kc = 0; kc < 6; ++kc) {
    const float* src = (kc < 4)
        ? (x1 + ((long)b * 128 + kc * 32) * 65536)
        : (x2 + ((long)b * 64 + (kc - 4) * 32) * 65536);
    const float* s8 = src + (long)(quad * 8) * 65536;

    // 8 float4 loads per lane: e[j][c] = act[ch=quad*8+j][px=pxl+c]
    float e[8][4];
    #pragma unroll
    for (int j = 0; j < 8; ++j)
      *(float4*)&e[j][0] = *(const float4*)(s8 + (long)j * 65536 + pxl);

    // weight fragments (L2-hot, same addresses across all blocks)
    bf16x8 af[4];
    #pragma unroll
    for (int mt = 0; mt < 4; ++mt) {
      const float* wrow = w0 + (mt * 16 + l16) * 192 + kc * 32 + quad * 8;
      float4 wa = *(const float4*)wrow;
      float4 wb = *(const float4*)(wrow + 4);
      union { unsigned i[4]; bf16x8 v; } u;
      u.i[0] = pk2(wa.x, wa.y); u.i[1] = pk2(wa.z, wa.w);
      u.i[2] = pk2(wb.x, wb.y); u.i[3] = pk2(wb.z, wb.w);
      af[mt] = u.v;
    }

    // B-frags: tile nt takes component nt of each float4
    bf16x8 bfv[4];
    #pragma unroll
    for (int nt = 0; nt < 4; ++nt) {
      union { unsigned i[4]; bf16x8 v; } u;
      #pragma unroll
      for (int j = 0; j < 4; ++j)
        u.i[j] = pk2(e[2 * j][nt], e[2 * j + 1][nt]);
      bfv[nt] = u.v;
    }
    #pragma unroll
    for (int mt = 0; mt < 4; ++mt)
      #pragma unroll
      for (int nt = 0; nt < 4; ++nt)
        acc[mt][nt] = __builtin_amdgcn_mfma_f32_16x16x32_bf16(
            af[mt], bfv[nt], acc[mt][nt], 0, 0, 0);
  }

  // epilogue: float4 stores; lane's 4 consecutive px = the 4 nt values
  #pragma unroll
  for (int mt = 0; mt < 4; ++mt) {
    const float4 bb = *(const float4*)(b0 + mt * 16 + quad * 4);
    #pragma unroll
    for (int r = 0; r < 4; ++r) {
      const int o = mt * 16 + quad * 4 + r;
      const float bias = (r == 0) ? bb.x : (r == 1) ? bb.y : (r == 2) ? bb.z : bb.w;
      float4 ov;
      ov.x = fmaxf(acc[mt][0][r] + bias, 0.f);
      ov.y = fmaxf(acc[mt][1][r] + bias, 0.f);
      ov.z = fmaxf(acc[mt][2][r] + bias, 0.f);
      ov.w = fmaxf(acc[mt][3][r] + bias, 0.f);
      *(float4*)(xout + ((long)b * 64 + o) * 65536 + pxl) = ov;
    }
  }

  // down4 copy: w%4==0 <=> nt==0 (pxl is a multiple of 4); h%4==0 <=> bx%4==0
  if ((blockIdx.x & 3) == 0) {
    const int n = (blockIdx.x >> 2) * 64 + wv * 16 + l16;
    #pragma unroll
    for (int mt = 0; mt < 4; ++mt) {
      const float4 bb = *(const float4*)(b0 + mt * 16 + quad * 4);
      const float v0 = fmaxf(acc[mt][0][0] + bb.x, 0.f);
      const float v1 = fmaxf(acc[mt][0][1] + bb.y, 0.f);
      const float v2 = fmaxf(acc[mt][0][2] + bb.z, 0.f);
      const float v3 = fmaxf(acc[mt][0][3] + bb.w, 0.f);
      union { unsigned i[2]; unsigned long long q; } u;
      u.i[0] = pk2(v0, v1); u.i[1] = pk2(v2, v3);
      *(unsigned long long*)(xds + ((long)b * 4096 + n) * 64 + mt * 16 + quad * 4) = u.q;
    }
  }
}

// ---------------------------------------------------------------------------
// K2: down4-res convs as chained 64x64x64 MFMA GEMMs through LDS (unchanged)
// ---------------------------------------------------------------------------
__device__ __forceinline__ void loadw_frag(const float* __restrict__ w,
                                           int row, int quad, bf16x8 wf[2]) {
  #pragma unroll
  for (int kc = 0; kc < 2; ++kc) {
    const float* p = w + row * 64 + kc * 32 + quad * 8;
    float4 a = *(const float4*)p;
    float4 c = *(const float4*)(p + 4);
    union { unsigned i[4]; bf16x8 v; } u;
    u.i[0] = pk2(a.x, a.y); u.i[1] = pk2(a.z, a.w);
    u.i[2] = pk2(c.x, c.y); u.i[3] = pk2(c.z, c.w);
    wf[kc] = u.v;
  }
}

__device__ __forceinline__ void conv_mfma(const short (*src)[72], short (*dst)[72],
                                          const bf16x8* wf,
                                          const float* __restrict__ bias,
                                          int ch0, int l16, int quad) {
  const float4 bv4 = *(const float4*)(bias + ch0);
  #pragma unroll
  for (int nt = 0; nt < 4; ++nt) {
    f32x4 acc = (f32x4){0.f, 0.f, 0.f, 0.f};
    #pragma unroll
    for (int kc = 0; kc < 2; ++kc) {
      bf16x8 bv = *(const bf16x8*)&src[nt * 16 + l16][kc * 32 + quad * 8];
      acc = __builtin_amdgcn_mfma_f32_16x16x32_bf16(wf[kc], bv, acc, 0, 0, 0);
    }
    const float v0 = fmaxf(acc[0] + bv4.x, 0.f);
    const float v1 = fmaxf(acc[1] + bv4.y, 0.f);
    const float v2 = fmaxf(acc[2] + bv4.z, 0.f);
    const float v3 = fmaxf(acc[3] + bv4.w, 0.f);
    union { unsigned i[2]; unsigned long long q; } u;
    u.i[0] = pk2(v0, v1); u.i[1] = pk2(v2, v3);
    *(unsigned long long*)&dst[nt * 16 + l16][ch0] = u.q;
  }
}

__global__ __launch_bounds__(256) void k2_small(
    const short* __restrict__ xds, const float* __restrict__ event,
    const float* __restrict__ xw1, const float* __restrict__ xb1,
    const float* __restrict__ ew0, const float* __restrict__ eb0,
    const float* __restrict__ ew1, const float* __restrict__ eb1,
    const float* __restrict__ qw, const float* __restrict__ qb,
    const float* __restrict__ kw, const float* __restrict__ kb,
    const float* __restrict__ vw, const float* __restrict__ vb,
    short* __restrict__ q_pm, short* __restrict__ k_pm,
    short* __restrict__ v_cm, short* __restrict__ ef_cm)
{
  __shared__ short A[64][72], Bb[64][72], Cb[64][72];
  const int b    = blockIdx.y;
  const int h4   = blockIdx.x;
  const int t    = threadIdx.x;
  const int lane = t & 63;
  const int g    = t >> 6;
  const int quad = lane >> 4;
  const int l16  = lane & 15;
  const int row  = g * 16 + l16;
  const int ch0  = g * 16 + quad * 4;

  bf16x8 wfx1[2], wfq[2], wfv[2], wfe0[2], wfe1[2], wfk[2];
  loadw_frag(xw1, row, quad, wfx1);
  loadw_frag(qw,  row, quad, wfq);
  loadw_frag(vw,  row, quad, wfv);
  loadw_frag(ew0, row, quad, wfe0);
  loadw_frag(ew1, row, quad, wfe1);
  loadw_frag(kw,  row, quad, wfk);

  const int px  = t >> 2;
  const int seg = t & 3;
  {
    const short* s = xds + ((long)b * 4096 + h4 * 64 + px) * 64 + seg * 16;
    *(bf16x8*)&A[px][seg * 16]     = *(const bf16x8*)s;
    *(bf16x8*)&A[px][seg * 16 + 8] = *(const bf16x8*)(s + 8);
  }
  __syncthreads();
  conv_mfma(A, Bb, wfx1, xb1, ch0, l16, quad);
  __syncthreads();
  conv_mfma(Bb, A,  wfq, qb, ch0, l16, quad);
  conv_mfma(Bb, Cb, wfv, vb, ch0, l16, quad);
  __syncthreads();
  {
    short* qdst = q_pm + ((long)b * 4096 + h4 * 64 + px) * 64 + seg * 16;
    *(bf16x8*)qdst       = *(const bf16x8*)&A[px][seg * 16];
    *(bf16x8*)(qdst + 8) = *(const bf16x8*)&A[px][seg * 16 + 8];
    union { short s[16]; int4 q2[2]; } vv;
    #pragma unroll
    for (int i = 0; i < 16; ++i) vv.s[i] = Cb[seg * 16 + i][px];
    int4* vdst = (int4*)(v_cm + ((long)b * 64 + px) * 4096 + h4 * 64 + seg * 16);
    vdst[0] = vv.q2[0]; vdst[1] = vv.q2[1];
    const int px2 = t & 63, cg = t >> 6;
    const float* ev = event + (long)b * 64 * 65536 + (long)h4 * 1024 + px2 * 4;
    #pragma unroll
    for (int r = 0; r < 16; r += 2) {
      const float e0v = ev[(long)(cg * 16 + r) * 65536];
      const float e1v = ev[(long)(cg * 16 + r + 1) * 65536];
      *(unsigned*)&Bb[px2][cg * 16 + r] = pk2(e0v, e1v);
    }
  }
  __syncthreads();
  conv_mfma(Bb, A,  wfe0, eb0, ch0, l16, quad);
  __syncthreads();
  conv_mfma(A,  Cb, wfe1, eb1, ch0, l16, quad);
  __syncthreads();
  conv_mfma(Cb, Bb, wfk, kb, ch0, l16, quad);
  {
    union { short s[16]; int4 q2[2]; } vv;
    #pragma unroll
    for (int i = 0; i < 16; ++i) vv.s[i] = Cb[seg * 16 + i][px];
    int4* edst = (int4*)(ef_cm + ((long)b * 64 + px) * 4096 + h4 * 64 + seg * 16);
    edst[0] = vv.q2[0]; edst[1] = vv.q2[1];
  }
  __syncthreads();
  {
    short* kdst = k_pm + ((long)b * 4096 + h4 * 64 + px) * 64 + seg * 16;
    *(bf16x8*)kdst       = *(const bf16x8*)&Bb[px][seg * 16];
    *(bf16x8*)(kdst + 8) = *(const bf16x8*)&Bb[px][seg * 16 + 8];
  }
}

// ---------------------------------------------------------------------------
// K3: flash attention, transposed orientation, split-K by 4. (unchanged)
// ---------------------------------------------------------------------------
__global__ __launch_bounds__(256, 4) void k3_attn(
    const short* __restrict__ q_pm, const short* __restrict__ k_pm,
    const short* __restrict__ v_cm, short* __restrict__ Opart,
    float* __restrict__ ml)
{
  __shared__ short Kf[2][4096];
  __shared__ short Vf[2][4096];
  __shared__ short Pf[4][2][512];
  const int b    = blockIdx.y;
  const int ks   = blockIdx.z;
  const int q0   = blockIdx.x * 64;
  const int t    = threadIdx.x;
  const int wv   = __builtin_amdgcn_readfirstlane(t >> 6);
  const int lane = t & 63;
  const int quad = lane >> 4;
  const int l16  = lane & 15;

  bf16x8 qf[2];
  {
    const short* qp = q_pm + ((long)b * 4096 + q0 + wv * 16 + l16) * 64 + quad * 8;
    qf[0] = *(const bf16x8*)qp;
    qf[1] = *(const bf16x8*)(qp + 32);
  }

  const int srow  = t >> 2;
  const int seg   = t & 3;
  const int doff0 = (((seg >> 1) * 4 + (srow >> 4)) * 64 +
                     ((seg & 1) * 2) * 16 + (srow & 15)) * 8;
  const short* kbase = k_pm + (long)b * 4096 * 64;
  const short* vbase = v_cm + (long)b * 64 * 4096;
  const int kt0 = ks * 16;

  bf16x8 krg[2], vrg[2];
  {
    const short* s = kbase + (long)(kt0 * 64 + srow) * 64 + seg * 16;
    krg[0] = *(const bf16x8*)s; krg[1] = *(const bf16x8*)(s + 8);
    const short* v = vbase + (long)srow * 4096 + kt0 * 64 + seg * 16;
    vrg[0] = *(const bf16x8*)v; vrg[1] = *(const bf16x8*)(v + 8);
  }
  *(bf16x8*)&Kf[0][doff0]       = krg[0];
  *(bf16x8*)&Kf[0][doff0 + 128] = krg[1];
  *(bf16x8*)&Vf[0][doff0]       = vrg[0];
  *(bf16x8*)&Vf[0][doff0 + 128] = vrg[1];
  __syncthreads();

  f32x4 oacc[4];
  #pragma unroll
  for (int f = 0; f < 4; ++f) oacc[f] = (f32x4){0, 0, 0, 0};
  float run_m = -1e30f, run_l = 0.f;

  for (int kt = 0; kt < 16; ++kt) {
    if (kt < 15) {
      const int k0 = (kt0 + kt + 1) * 64;
      const short* s = kbase + (long)(k0 + srow) * 64 + seg * 16;
      krg[0] = *(const bf16x8*)s; krg[1] = *(const bf16x8*)(s + 8);
      const short* v = vbase + (long)srow * 4096 + k0 + seg * 16;
      vrg[0] = *(const bf16x8*)v; vrg[1] = *(const bf16x8*)(v + 8);
    }
    const int buf = kt & 1;

    f32x4 st[4];
    #pragma unroll
    for (int f = 0; f < 4; ++f) st[f] = (f32x4){0, 0, 0, 0};
    #pragma unroll
    for (int kc = 0; kc < 2; ++kc)
      #pragma unroll
      for (int f = 0; f < 4; ++f) {
        bf16x8 ka = *(const bf16x8*)&Kf[buf][((kc * 4 + f) * 64 + lane) * 8];
        st[f] = __builtin_amdgcn_mfma_f32_16x16x32_bf16(ka, qf[kc], st[f], 0, 0, 0);
      }

    float tm = st[0][0];
    #pragma unroll
    for (int f = 0; f < 4; ++f)
      #pragma unroll
      for (int r = 0; r < 4; ++r) tm = fmaxf(tm, st[f][r]);
    tm = fmaxf(tm, __shfl_xor(tm, 16));
    tm = fmaxf(tm, __shfl_xor(tm, 32));
    const float nm = fmaxf(run_m, tm);
    const float al = __expf(run_m - nm);
    run_m = nm;
    float pf[4][4], ts = 0.f;
    #pragma unroll
    for (int f = 0; f < 4; ++f)
      #pragma unroll
      for (int r = 0; r < 4; ++r) {
        pf[f][r] = __expf(st[f][r] - nm);
        ts += pf[f][r];
      }
    ts += __shfl_xor(ts, 16);
    ts += __shfl_xor(ts, 32);
    run_l = run_l * al + ts;
    #pragma unroll
    for (int f = 0; f < 4; ++f)
      #pragma unroll
      for (int r = 0; r < 4; ++r) oacc[f][r] *= al;

    #pragma unroll
    for (int f = 0; f < 4; ++f) {
      union { unsigned i[2]; unsigned long long q; } u;
      u.i[0] = pk2(pf[f][0], pf[f][1]);
      u.i[1] = pk2(pf[f][2], pf[f][3]);
      const int qd = (f & 1) * 2 + (quad >> 1);
      *(unsigned long long*)&Pf[wv][f >> 1][(qd * 16 + l16) * 8 + (quad & 1) * 4] = u.q;
    }
    #pragma unroll
    for (int kc = 0; kc < 2; ++kc) {
      bf16x8 pb = *(const bf16x8*)&Pf[wv][kc][lane * 8];
      #pragma unroll
      for (int f = 0; f < 4; ++f) {
        bf16x8 va = *(const bf16x8*)&Vf[buf][((kc * 4 + f) * 64 + lane) * 8];
        oacc[f] = __builtin_amdgcn_mfma_f32_16x16x32_bf16(va, pb, oacc[f], 0, 0, 0);
      }
    }

    if (kt < 15) {
      const int nb = buf ^ 1;
      *(bf16x8*)&Kf[nb][doff0]       = krg[0];
      *(bf16x8*)&Kf[nb][doff0 + 128] = krg[1];
      *(bf16x8*)&Vf[nb][doff0]       = vrg[0];
      *(bf16x8*)&Vf[nb][doff0 + 128] = vrg[1];
      __syncthreads();
    }
  }

  const int q = q0 + wv * 16 + l16;
  #pragma unroll
  for (int f = 0; f < 4; ++f)
    #pragma unroll
    for (int r = 0; r < 4; ++r) {
      const int ch = f * 16 + quad * 4 + r;
      Opart[((long)(ks * 4 + b) * 64 + ch) * 4096 + q] = f2bf_s(oacc[f][r]);
    }
  if (quad == 0) {
    float2 v = make_float2(run_m, run_l);
    *(float2*)&ml[((long)(ks * 4 + b) * 4096 + q) * 2] = v;
  }
}

// ---------------------------------------------------------------------------
// K3W: combine weights per (b,q) (unchanged)
// ---------------------------------------------------------------------------
__global__ __launch_bounds__(256) void k3w(const float* __restrict__ ml,
                                           float* __restrict__ wc)
{
  const int idx = blockIdx.x * 256 + threadIdx.x;
  const float2* m2 = (const float2*)ml;
  float2 s0 = m2[0 * 16384 + idx];
  float2 s1 = m2[1 * 16384 + idx];
  float2 s2 = m2[2 * 16384 + idx];
  float2 s3 = m2[3 * 16384 + idx];
  const float M = fmaxf(fmaxf(s0.x, s1.x), fmaxf(s2.x, s3.x));
  const float e0 = __expf(s0.x - M), e1 = __expf(s1.x - M);
  const float e2 = __expf(s2.x - M), e3 = __expf(s3.x - M);
  const float inv = 1.f / (e0 * s0.y + e1 * s1.y + e2 * s2.y + e3 * s3.y);
  *(float4*)&wc[idx * 4] = make_float4(e0 * inv, e1 * inv, e2 * inv, e3 * inv);
}

// ---------------------------------------------------------------------------
// K4: out = x + THITA*gamma*up4(combine(Opart));  ef_up = up4(ef). (unchanged)
// ---------------------------------------------------------------------------
__global__ __launch_bounds__(256) void k4_final(
    const short* __restrict__ Opart, const float* __restrict__ wc,
    const short* __restrict__ ef_cm, const float* __restrict__ gamma,
    float* __restrict__ dout)
{
  const long idx = (long)blockIdx.x * 256 + threadIdx.x;
  const long e4 = idx * 4;
  const int hw = (int)(e4 & 65535);
  const int bc = (int)(e4 >> 16);
  const int h = hw >> 8, w0 = hw & 255;
  const int n = (h >> 2) * 64 + (w0 >> 2);
  const int b = bc >> 6, c = bc & 63;
  const float s = 1e-4f * gamma[0];
  const float4 w4 = *(const float4*)&wc[((long)b * 4096 + n) * 4];
  const long obase = ((long)b * 64 + c) * 4096 + n;
  float ov = w4.x * bf2f(Opart[obase]) +
             w4.y * bf2f(Opart[obase + (long)1 * 4 * 64 * 4096]) +
             w4.z * bf2f(Opart[obase + (long)2 * 4 * 64 * 4096]) +
             w4.w * bf2f(Opart[obase + (long)3 * 4 * 64 * 4096]);
  ov *= s;
  float4 xv = *(float4*)(dout + e4);
  xv.x += ov; xv.y += ov; xv.z += ov; xv.w += ov;
  *(float4*)(dout + e4) = xv;
  const float ef = bf2f(ef_cm[(long)bc * 4096 + n]);
  *(float4*)(dout + 16777216 + e4) = make_float4(ef, ef, ef, ef);
}

extern "C" void kernel_launch(void* const* d_in, const int* in_sizes, int n_in,
                              void* d_out, int out_size, void* d_ws, size_t ws_size,
                              hipStream_t stream)
{
  const float* x1    = (const float*)d_in[0];
  const float* x2    = (const float*)d_in[1];
  const float* event = (const float*)d_in[2];
  const float* xw0   = (const float*)d_in[3];
  const float* xb0   = (const float*)d_in[4];
  const float* xw1   = (const float*)d_in[5];
  const float* xb1   = (const float*)d_in[6];
  const float* ew0   = (const float*)d_in[7];
  const float* eb0   = (const float*)d_in[8];
  const float* ew1   = (const float*)d_in[9];
  const float* eb1   = (const float*)d_in[10];
  const float* qw    = (const float*)d_in[11];
  const float* qb    = (const float*)d_in[12];
  const float* kw    = (const float*)d_in[13];
  const float* kb    = (const float*)d_in[14];
  const float* vw    = (const float*)d_in[15];
  const float* vb    = (const float*)d_in[16];
  const float* gamma = (const float*)d_in[17];
  float* dout = (float*)d_out;

  char* ws = (char*)d_ws;
  short* q_pm  = (short*)(ws);
  short* k_pm  = (short*)(ws + (2u << 20));
  short* v_cm  = (short*)(ws + (4u << 20));
  short* ef_cm = (short*)(ws + (6u << 20));
  short* xds   = (short*)(ws + (8u << 20));
  short* Opart = (short*)(ws + (10u << 20));
  float* ml    = (float*)(ws + (18u << 20));
  float* wc    = (float*)(ws + (18u << 20) + (512u << 10));

  k1_conv192<<<dim3(256, 4), 256, 0, stream>>>(x1, x2, xw0, xb0, dout, xds);
  k2_small<<<dim3(64, 4), 256, 0, stream>>>(xds, event, xw1, xb1, ew0, eb0,
                                            ew1, eb1, qw, qb, kw, kb, vw, vb,
                                            q_pm, k_pm, v_cm, ef_cm);
  k3_attn<<<dim3(64, 4, 4), 256, 0, stream>>>(q_pm, k_pm, v_cm, Opart, ml);
  k3w<<<64, 256, 0, stream>>>(ml, wc);
  k4_final<<<16384, 256, 0, stream>>>(Opart, wc, ef_cm, gamma, dout);
}

// Round 5
// 409.518 us; speedup vs baseline: 1.1078x; 1.0232x over previous
//
#include <hip/hip_runtime.h>

typedef __attribute__((ext_vector_type(8))) short bf16x8;
typedef __attribute__((ext_vector_type(4))) float f32x4;

// pack two fp32 -> two bf16 (round-half-up) in one v_perm_b32
__device__ __forceinline__ unsigned pk2(float f0, float f1) {
  return __builtin_amdgcn_perm(__float_as_uint(f1) + 0x8000u,
                               __float_as_uint(f0) + 0x8000u, 0x07060302u);
}
__device__ __forceinline__ short f2bf_s(float f) {
  return (short)((__float_as_uint(f) + 0x8000u) >> 16);
}
__device__ __forceinline__ float bf2f(short s) {
  return __uint_as_float(((unsigned)(unsigned short)s) << 16);
}

// ---------------------------------------------------------------------------
// K1: full-res conv 192->64 + bias + relu; also emits compact down4 copy.
// v6: R4's float4 structure + sched_barrier(0)-enforced software pipeline.
// All 24 weight frags preloaded BEFORE the k-loop (so the activation vmcnt
// queue is pure); tile kc+1's 8 float4 loads are issued, then SB(0) pins them
// ahead of tile kc's pack+MFMA -- the compiler cannot sink them to their use
// site (which is what silently defeated R2 and R4; VGPR_Count=68 both times).
// If VGPR>=150 and BW still ~1.7 TB/s, the planar-stride pattern wall is
// confirmed by elimination.
// ---------------------------------------------------------------------------
__global__ __launch_bounds__(256, 2) void k1_conv192(
    const float* __restrict__ x1, const float* __restrict__ x2,
    const float* __restrict__ w0, const float* __restrict__ b0,
    float* __restrict__ xout, short* __restrict__ xds)
{
  const int b    = blockIdx.y;
  const int wv   = threadIdx.x >> 6;
  const int lane = threadIdx.x & 63;
  const int quad = lane >> 4;
  const int l16  = lane & 15;
  const int n0   = blockIdx.x * 256 + wv * 64;
  const int pxl  = n0 + 4 * l16;            // this lane's first pixel

  // ---- all weight fragments up front (complete early; L2-hot) ----
  bf16x8 af[6][4];
  #pragma unroll
  for (int kc = 0; kc < 6; ++kc)
    #pragma unroll
    for (int mt = 0; mt < 4; ++mt) {
      const float* wrow = w0 + (mt * 16 + l16) * 192 + kc * 32 + quad * 8;
      float4 wa = *(const float4*)wrow;
      float4 wb = *(const float4*)(wrow + 4);
      union { unsigned i[4]; bf16x8 v; } u;
      u.i[0] = pk2(wa.x, wa.y); u.i[1] = pk2(wa.z, wa.w);
      u.i[2] = pk2(wb.x, wb.y); u.i[3] = pk2(wb.z, wb.w);
      af[kc][mt] = u.v;
    }

  f32x4 acc[4][4];
  #pragma unroll
  for (int mt = 0; mt < 4; ++mt)
    #pragma unroll
    for (int nt = 0; nt < 4; ++nt)
      acc[mt][nt] = (f32x4){0.f, 0.f, 0.f, 0.f};

  // activation register double-buffer: e[buf][j] = float4 of 4 px, ch j
  float e[2][8][4];

  auto issue = [&](int kc, int buf) {
    const float* src = (kc < 4)
        ? (x1 + ((long)b * 128 + kc * 32) * 65536)
        : (x2 + ((long)b * 64 + (kc - 4) * 32) * 65536);
    const float* s8 = src + (long)(quad * 8) * 65536;
    #pragma unroll
    for (int j = 0; j < 8; ++j)
      *(float4*)&e[buf][j][0] = *(const float4*)(s8 + (long)j * 65536 + pxl);
  };

  issue(0, 0);
  __builtin_amdgcn_sched_barrier(0);

  #pragma unroll
  for (int kc = 0; kc < 6; ++kc) {
    if (kc < 5) issue(kc + 1, (kc + 1) & 1);
    __builtin_amdgcn_sched_barrier(0);   // pin prefetch ahead of consume

    bf16x8 bfv[4];
    #pragma unroll
    for (int nt = 0; nt < 4; ++nt) {
      union { unsigned i[4]; bf16x8 v; } u;
      #pragma unroll
      for (int j = 0; j < 4; ++j)
        u.i[j] = pk2(e[kc & 1][2 * j][nt], e[kc & 1][2 * j + 1][nt]);
      bfv[nt] = u.v;
    }
    #pragma unroll
    for (int mt = 0; mt < 4; ++mt)
      #pragma unroll
      for (int nt = 0; nt < 4; ++nt)
        acc[mt][nt] = __builtin_amdgcn_mfma_f32_16x16x32_bf16(
            af[kc][mt], bfv[nt], acc[mt][nt], 0, 0, 0);
  }

  // epilogue: float4 stores; lane's 4 consecutive px = the 4 nt values
  #pragma unroll
  for (int mt = 0; mt < 4; ++mt) {
    const float4 bb = *(const float4*)(b0 + mt * 16 + quad * 4);
    #pragma unroll
    for (int r = 0; r < 4; ++r) {
      const int o = mt * 16 + quad * 4 + r;
      const float bias = (r == 0) ? bb.x : (r == 1) ? bb.y : (r == 2) ? bb.z : bb.w;
      float4 ov;
      ov.x = fmaxf(acc[mt][0][r] + bias, 0.f);
      ov.y = fmaxf(acc[mt][1][r] + bias, 0.f);
      ov.z = fmaxf(acc[mt][2][r] + bias, 0.f);
      ov.w = fmaxf(acc[mt][3][r] + bias, 0.f);
      *(float4*)(xout + ((long)b * 64 + o) * 65536 + pxl) = ov;
    }
  }

  // down4 copy: w%4==0 <=> nt==0 (pxl is a multiple of 4); h%4==0 <=> bx%4==0
  if ((blockIdx.x & 3) == 0) {
    const int n = (blockIdx.x >> 2) * 64 + wv * 16 + l16;
    #pragma unroll
    for (int mt = 0; mt < 4; ++mt) {
      const float4 bb = *(const float4*)(b0 + mt * 16 + quad * 4);
      const float v0 = fmaxf(acc[mt][0][0] + bb.x, 0.f);
      const float v1 = fmaxf(acc[mt][0][1] + bb.y, 0.f);
      const float v2 = fmaxf(acc[mt][0][2] + bb.z, 0.f);
      const float v3 = fmaxf(acc[mt][0][3] + bb.w, 0.f);
      union { unsigned i[2]; unsigned long long q; } u;
      u.i[0] = pk2(v0, v1); u.i[1] = pk2(v2, v3);
      *(unsigned long long*)(xds + ((long)b * 4096 + n) * 64 + mt * 16 + quad * 4) = u.q;
    }
  }
}

// ---------------------------------------------------------------------------
// K2: down4-res convs as chained 64x64x64 MFMA GEMMs through LDS.
// v2: the 16 strided event loads (a bare-latency serial stall mid-kernel)
// are issued at kernel start and consumed at the original site ~3 GEMM
// phases later; precise compiler vmcnt(N) keeps them outstanding while the
// earlier xds/weight loads are consumed.
// ---------------------------------------------------------------------------
__device__ __forceinline__ void loadw_frag(const float* __restrict__ w,
                                           int row, int quad, bf16x8 wf[2]) {
  #pragma unroll
  for (int kc = 0; kc < 2; ++kc) {
    const float* p = w + row * 64 + kc * 32 + quad * 8;
    float4 a = *(const float4*)p;
    float4 c = *(const float4*)(p + 4);
    union { unsigned i[4]; bf16x8 v; } u;
    u.i[0] = pk2(a.x, a.y); u.i[1] = pk2(a.z, a.w);
    u.i[2] = pk2(c.x, c.y); u.i[3] = pk2(c.z, c.w);
    wf[kc] = u.v;
  }
}

__device__ __forceinline__ void conv_mfma(const short (*src)[72], short (*dst)[72],
                                          const bf16x8* wf,
                                          const float* __restrict__ bias,
                                          int ch0, int l16, int quad) {
  const float4 bv4 = *(const float4*)(bias + ch0);
  #pragma unroll
  for (int nt = 0; nt < 4; ++nt) {
    f32x4 acc = (f32x4){0.f, 0.f, 0.f, 0.f};
    #pragma unroll
    for (int kc = 0; kc < 2; ++kc) {
      bf16x8 bv = *(const bf16x8*)&src[nt * 16 + l16][kc * 32 + quad * 8];
      acc = __builtin_amdgcn_mfma_f32_16x16x32_bf16(wf[kc], bv, acc, 0, 0, 0);
    }
    const float v0 = fmaxf(acc[0] + bv4.x, 0.f);
    const float v1 = fmaxf(acc[1] + bv4.y, 0.f);
    const float v2 = fmaxf(acc[2] + bv4.z, 0.f);
    const float v3 = fmaxf(acc[3] + bv4.w, 0.f);
    union { unsigned i[2]; unsigned long long q; } u;
    u.i[0] = pk2(v0, v1); u.i[1] = pk2(v2, v3);
    *(unsigned long long*)&dst[nt * 16 + l16][ch0] = u.q;
  }
}

__global__ __launch_bounds__(256) void k2_small(
    const short* __restrict__ xds, const float* __restrict__ event,
    const float* __restrict__ xw1, const float* __restrict__ xb1,
    const float* __restrict__ ew0, const float* __restrict__ eb0,
    const float* __restrict__ ew1, const float* __restrict__ eb1,
    const float* __restrict__ qw, const float* __restrict__ qb,
    const float* __restrict__ kw, const float* __restrict__ kb,
    const float* __restrict__ vw, const float* __restrict__ vb,
    short* __restrict__ q_pm, short* __restrict__ k_pm,
    short* __restrict__ v_cm, short* __restrict__ ef_cm)
{
  __shared__ short A[64][72], Bb[64][72], Cb[64][72];
  const int b    = blockIdx.y;
  const int h4   = blockIdx.x;
  const int t    = threadIdx.x;
  const int lane = t & 63;
  const int g    = t >> 6;
  const int quad = lane >> 4;
  const int l16  = lane & 15;
  const int row  = g * 16 + l16;
  const int ch0  = g * 16 + quad * 4;

  bf16x8 wfx1[2], wfq[2], wfv[2], wfe0[2], wfe1[2], wfk[2];
  loadw_frag(xw1, row, quad, wfx1);
  loadw_frag(qw,  row, quad, wfq);
  loadw_frag(vw,  row, quad, wfv);
  loadw_frag(ew0, row, quad, wfe0);
  loadw_frag(ew1, row, quad, wfe1);
  loadw_frag(kw,  row, quad, wfk);

  const int px  = t >> 2;
  const int seg = t & 3;
  {
    const short* s = xds + ((long)b * 4096 + h4 * 64 + px) * 64 + seg * 16;
    *(bf16x8*)&A[px][seg * 16]     = *(const bf16x8*)s;
    *(bf16x8*)&A[px][seg * 16 + 8] = *(const bf16x8*)(s + 8);
  }

  // early-issue the strided event loads; consumed 3 GEMM phases later
  float evv[16];
  {
    const int px2 = t & 63, cg = t >> 6;
    const float* ev = event + (long)b * 64 * 65536 + (long)h4 * 1024 + px2 * 4;
    #pragma unroll
    for (int r = 0; r < 16; ++r)
      evv[r] = ev[(long)(cg * 16 + r) * 65536];
  }
  __builtin_amdgcn_sched_barrier(0);

  __syncthreads();
  conv_mfma(A, Bb, wfx1, xb1, ch0, l16, quad);
  __syncthreads();
  conv_mfma(Bb, A,  wfq, qb, ch0, l16, quad);
  conv_mfma(Bb, Cb, wfv, vb, ch0, l16, quad);
  __syncthreads();
  {
    short* qdst = q_pm + ((long)b * 4096 + h4 * 64 + px) * 64 + seg * 16;
    *(bf16x8*)qdst       = *(const bf16x8*)&A[px][seg * 16];
    *(bf16x8*)(qdst + 8) = *(const bf16x8*)&A[px][seg * 16 + 8];
    union { short s[16]; int4 q2[2]; } vv;
    #pragma unroll
    for (int i = 0; i < 16; ++i) vv.s[i] = Cb[seg * 16 + i][px];
    int4* vdst = (int4*)(v_cm + ((long)b * 64 + px) * 4096 + h4 * 64 + seg * 16);
    vdst[0] = vv.q2[0]; vdst[1] = vv.q2[1];
    const int px2 = t & 63, cg = t >> 6;
    #pragma unroll
    for (int r = 0; r < 16; r += 2)
      *(unsigned*)&Bb[px2][cg * 16 + r] = pk2(evv[r], evv[r + 1]);
  }
  __syncthreads();
  conv_mfma(Bb, A,  wfe0, eb0, ch0, l16, quad);
  __syncthreads();
  conv_mfma(A,  Cb, wfe1, eb1, ch0, l16, quad);
  __syncthreads();
  conv_mfma(Cb, Bb, wfk, kb, ch0, l16, quad);
  {
    union { short s[16]; int4 q2[2]; } vv;
    #pragma unroll
    for (int i = 0; i < 16; ++i) vv.s[i] = Cb[seg * 16 + i][px];
    int4* edst = (int4*)(ef_cm + ((long)b * 64 + px) * 4096 + h4 * 64 + seg * 16);
    edst[0] = vv.q2[0]; edst[1] = vv.q2[1];
  }
  __syncthreads();
  {
    short* kdst = k_pm + ((long)b * 4096 + h4 * 64 + px) * 64 + seg * 16;
    *(bf16x8*)kdst       = *(const bf16x8*)&Bb[px][seg * 16];
    *(bf16x8*)(kdst + 8) = *(const bf16x8*)&Bb[px][seg * 16 + 8];
  }
}

// ---------------------------------------------------------------------------
// K3: flash attention, transposed orientation, split-K by 4. (unchanged)
// ---------------------------------------------------------------------------
__global__ __launch_bounds__(256, 4) void k3_attn(
    const short* __restrict__ q_pm, const short* __restrict__ k_pm,
    const short* __restrict__ v_cm, short* __restrict__ Opart,
    float* __restrict__ ml)
{
  __shared__ short Kf[2][4096];
  __shared__ short Vf[2][4096];
  __shared__ short Pf[4][2][512];
  const int b    = blockIdx.y;
  const int ks   = blockIdx.z;
  const int q0   = blockIdx.x * 64;
  const int t    = threadIdx.x;
  const int wv   = __builtin_amdgcn_readfirstlane(t >> 6);
  const int lane = t & 63;
  const int quad = lane >> 4;
  const int l16  = lane & 15;

  bf16x8 qf[2];
  {
    const short* qp = q_pm + ((long)b * 4096 + q0 + wv * 16 + l16) * 64 + quad * 8;
    qf[0] = *(const bf16x8*)qp;
    qf[1] = *(const bf16x8*)(qp + 32);
  }

  const int srow  = t >> 2;
  const int seg   = t & 3;
  const int doff0 = (((seg >> 1) * 4 + (srow >> 4)) * 64 +
                     ((seg & 1) * 2) * 16 + (srow & 15)) * 8;
  const short* kbase = k_pm + (long)b * 4096 * 64;
  const short* vbase = v_cm + (long)b * 64 * 4096;
  const int kt0 = ks * 16;

  bf16x8 krg[2], vrg[2];
  {
    const short* s = kbase + (long)(kt0 * 64 + srow) * 64 + seg * 16;
    krg[0] = *(const bf16x8*)s; krg[1] = *(const bf16x8*)(s + 8);
    const short* v = vbase + (long)srow * 4096 + kt0 * 64 + seg * 16;
    vrg[0] = *(const bf16x8*)v; vrg[1] = *(const bf16x8*)(v + 8);
  }
  *(bf16x8*)&Kf[0][doff0]       = krg[0];
  *(bf16x8*)&Kf[0][doff0 + 128] = krg[1];
  *(bf16x8*)&Vf[0][doff0]       = vrg[0];
  *(bf16x8*)&Vf[0][doff0 + 128] = vrg[1];
  __syncthreads();

  f32x4 oacc[4];
  #pragma unroll
  for (int f = 0; f < 4; ++f) oacc[f] = (f32x4){0, 0, 0, 0};
  float run_m = -1e30f, run_l = 0.f;

  for (int kt = 0; kt < 16; ++kt) {
    if (kt < 15) {
      const int k0 = (kt0 + kt + 1) * 64;
      const short* s = kbase + (long)(k0 + srow) * 64 + seg * 16;
      krg[0] = *(const bf16x8*)s; krg[1] = *(const bf16x8*)(s + 8);
      const short* v = vbase + (long)srow * 4096 + k0 + seg * 16;
      vrg[0] = *(const bf16x8*)v; vrg[1] = *(const bf16x8*)(v + 8);
    }
    const int buf = kt & 1;

    f32x4 st[4];
    #pragma unroll
    for (int f = 0; f < 4; ++f) st[f] = (f32x4){0, 0, 0, 0};
    #pragma unroll
    for (int kc = 0; kc < 2; ++kc)
      #pragma unroll
      for (int f = 0; f < 4; ++f) {
        bf16x8 ka = *(const bf16x8*)&Kf[buf][((kc * 4 + f) * 64 + lane) * 8];
        st[f] = __builtin_amdgcn_mfma_f32_16x16x32_bf16(ka, qf[kc], st[f], 0, 0, 0);
      }

    float tm = st[0][0];
    #pragma unroll
    for (int f = 0; f < 4; ++f)
      #pragma unroll
      for (int r = 0; r < 4; ++r) tm = fmaxf(tm, st[f][r]);
    tm = fmaxf(tm, __shfl_xor(tm, 16));
    tm = fmaxf(tm, __shfl_xor(tm, 32));
    const float nm = fmaxf(run_m, tm);
    const float al = __expf(run_m - nm);
    run_m = nm;
    float pf[4][4], ts = 0.f;
    #pragma unroll
    for (int f = 0; f < 4; ++f)
      #pragma unroll
      for (int r = 0; r < 4; ++r) {
        pf[f][r] = __expf(st[f][r] - nm);
        ts += pf[f][r];
      }
    ts += __shfl_xor(ts, 16);
    ts += __shfl_xor(ts, 32);
    run_l = run_l * al + ts;
    #pragma unroll
    for (int f = 0; f < 4; ++f)
      #pragma unroll
      for (int r = 0; r < 4; ++r) oacc[f][r] *= al;

    #pragma unroll
    for (int f = 0; f < 4; ++f) {
      union { unsigned i[2]; unsigned long long q; } u;
      u.i[0] = pk2(pf[f][0], pf[f][1]);
      u.i[1] = pk2(pf[f][2], pf[f][3]);
      const int qd = (f & 1) * 2 + (quad >> 1);
      *(unsigned long long*)&Pf[wv][f >> 1][(qd * 16 + l16) * 8 + (quad & 1) * 4] = u.q;
    }
    #pragma unroll
    for (int kc = 0; kc < 2; ++kc) {
      bf16x8 pb = *(const bf16x8*)&Pf[wv][kc][lane * 8];
      #pragma unroll
      for (int f = 0; f < 4; ++f) {
        bf16x8 va = *(const bf16x8*)&Vf[buf][((kc * 4 + f) * 64 + lane) * 8];
        oacc[f] = __builtin_amdgcn_mfma_f32_16x16x32_bf16(va, pb, oacc[f], 0, 0, 0);
      }
    }

    if (kt < 15) {
      const int nb = buf ^ 1;
      *(bf16x8*)&Kf[nb][doff0]       = krg[0];
      *(bf16x8*)&Kf[nb][doff0 + 128] = krg[1];
      *(bf16x8*)&Vf[nb][doff0]       = vrg[0];
      *(bf16x8*)&Vf[nb][doff0 + 128] = vrg[1];
      __syncthreads();
    }
  }

  const int q = q0 + wv * 16 + l16;
  #pragma unroll
  for (int f = 0; f < 4; ++f)
    #pragma unroll
    for (int r = 0; r < 4; ++r) {
      const int ch = f * 16 + quad * 4 + r;
      Opart[((long)(ks * 4 + b) * 64 + ch) * 4096 + q] = f2bf_s(oacc[f][r]);
    }
  if (quad == 0) {
    float2 v = make_float2(run_m, run_l);
    *(float2*)&ml[((long)(ks * 4 + b) * 4096 + q) * 2] = v;
  }
}

// ---------------------------------------------------------------------------
// K3W: combine weights per (b,q) (unchanged)
// ---------------------------------------------------------------------------
__global__ __launch_bounds__(256) void k3w(const float* __restrict__ ml,
                                           float* __restrict__ wc)
{
  const int idx = blockIdx.x * 256 + threadIdx.x;
  const float2* m2 = (const float2*)ml;
  float2 s0 = m2[0 * 16384 + idx];
  float2 s1 = m2[1 * 16384 + idx];
  float2 s2 = m2[2 * 16384 + idx];
  float2 s3 = m2[3 * 16384 + idx];
  const float M = fmaxf(fmaxf(s0.x, s1.x), fmaxf(s2.x, s3.x));
  const float e0 = __expf(s0.x - M), e1 = __expf(s1.x - M);
  const float e2 = __expf(s2.x - M), e3 = __expf(s3.x - M);
  const float inv = 1.f / (e0 * s0.y + e1 * s1.y + e2 * s2.y + e3 * s3.y);
  *(float4*)&wc[idx * 4] = make_float4(e0 * inv, e1 * inv, e2 * inv, e3 * inv);
}

// ---------------------------------------------------------------------------
// K4: out = x + THITA*gamma*up4(combine(Opart));  ef_up = up4(ef). (unchanged)
// ---------------------------------------------------------------------------
__global__ __launch_bounds__(256) void k4_final(
    const short* __restrict__ Opart, const float* __restrict__ wc,
    const short* __restrict__ ef_cm, const float* __restrict__ gamma,
    float* __restrict__ dout)
{
  const long idx = (long)blockIdx.x * 256 + threadIdx.x;
  const long e4 = idx * 4;
  const int hw = (int)(e4 & 65535);
  const int bc = (int)(e4 >> 16);
  const int h = hw >> 8, w0 = hw & 255;
  const int n = (h >> 2) * 64 + (w0 >> 2);
  const int b = bc >> 6, c = bc & 63;
  const float s = 1e-4f * gamma[0];
  const float4 w4 = *(const float4*)&wc[((long)b * 4096 + n) * 4];
  const long obase = ((long)b * 64 + c) * 4096 + n;
  float ov = w4.x * bf2f(Opart[obase]) +
             w4.y * bf2f(Opart[obase + (long)1 * 4 * 64 * 4096]) +
             w4.z * bf2f(Opart[obase + (long)2 * 4 * 64 * 4096]) +
             w4.w * bf2f(Opart[obase + (long)3 * 4 * 64 * 4096]);
  ov *= s;
  float4 xv = *(float4*)(dout + e4);
  xv.x += ov; xv.y += ov; xv.z += ov; xv.w += ov;
  *(float4*)(dout + e4) = xv;
  const float ef = bf2f(ef_cm[(long)bc * 4096 + n]);
  *(float4*)(dout + 16777216 + e4) = make_float4(ef, ef, ef, ef);
}

extern "C" void kernel_launch(void* const* d_in, const int* in_sizes, int n_in,
                              void* d_out, int out_size, void* d_ws, size_t ws_size,
                              hipStream_t stream)
{
  const float* x1    = (const float*)d_in[0];
  const float* x2    = (const float*)d_in[1];
  const float* event = (const float*)d_in[2];
  const float* xw0   = (const float*)d_in[3];
  const float* xb0   = (const float*)d_in[4];
  const float* xw1   = (const float*)d_in[5];
  const float* xb1   = (const float*)d_in[6];
  const float* ew0   = (const float*)d_in[7];
  const float* eb0   = (const float*)d_in[8];
  const float* ew1   = (const float*)d_in[9];
  const float* eb1   = (const float*)d_in[10];
  const float* qw    = (const float*)d_in[11];
  const float* qb    = (const float*)d_in[12];
  const float* kw    = (const float*)d_in[13];
  const float* kb    = (const float*)d_in[14];
  const float* vw    = (const float*)d_in[15];
  const float* vb    = (const float*)d_in[16];
  const float* gamma = (const float*)d_in[17];
  float* dout = (float*)d_out;

  char* ws = (char*)d_ws;
  short* q_pm  = (short*)(ws);
  short* k_pm  = (short*)(ws + (2u << 20));
  short* v_cm  = (short*)(ws + (4u << 20));
  short* ef_cm = (short*)(ws + (6u << 20));
  short* xds   = (short*)(ws + (8u << 20));
  short* Opart = (short*)(ws + (10u << 20));
  float* ml    = (float*)(ws + (18u << 20));
  float* wc    = (float*)(ws + (18u << 20) + (512u << 10));

  k1_conv192<<<dim3(256, 4), 256, 0, stream>>>(x1, x2, xw0, xb0, dout, xds);
  k2_small<<<dim3(64, 4), 256, 0, stream>>>(xds, event, xw1, xb1, ew0, eb0,
                                            ew1, eb1, qw, qb, kw, kb, vw, vb,
                                            q_pm, k_pm, v_cm, ef_cm);
  k3_attn<<<dim3(64, 4, 4), 256, 0, stream>>>(q_pm, k_pm, v_cm, Opart, ml);
  k3w<<<64, 256, 0, stream>>>(ml, wc);
  k4_final<<<16384, 256, 0, stream>>>(Opart, wc, ef_cm, gamma, dout);
}